// Round 1
// baseline (19.136 us; speedup 1.0000x reference)
//
#include <hip/hip_runtime.h>

// Problem geometry (fixed by the reference):
//   x: (16, 1, 2048, 2048) f32
//   k = 17 (WINDOW_RADIUS=8), L = 2048-17+1 = 2032
//   iv:   (16, 2032) f32   = log2(blockmean / global_mean(blockmean))
//   dv:   (16, 2017) f32   = mean(iv[j+8..j+15]) - mean(iv[j..j+7])
//   band: (16, 2015) bool  = (dv[j] < 0) & (dv[j+2] > 0)   (written as 0.0/1.0 f32)

#define NN    2048
#define KW    17
#define LL    2032          // NN - KW + 1
#define DS    8
#define LD    2017          // (LL - DS) - DS + 1
#define LB    2015
#define BATCH 16
#define TILES_A ((LL + 63) / 64)   // 32

// ---------------------------------------------------------------------------
// Kernel A: diagonal 17x17 block sums S[b,i] (f64), plus per-block partial
// sums of S for the global mean. 512 blocks x 64 threads (1 wave each).
// Accesses only the diagonal band of x; lines are L1/L2-reused heavily
// across the 289-element per-thread loop.
// ---------------------------------------------------------------------------
__global__ __launch_bounds__(64) void kA(const float* __restrict__ x,
                                         double* __restrict__ S,
                                         double* __restrict__ part) {
    const int b = blockIdx.y;
    const int i = blockIdx.x * 64 + threadIdx.x;
    const float* xb = x + (size_t)b * NN * NN;

    double s = 0.0;
    if (i < LL) {
        for (int dr = 0; dr < KW; ++dr) {
            const float* row = xb + (size_t)(i + dr) * NN + i;
            double rs = 0.0;
            #pragma unroll
            for (int dc = 0; dc < KW; ++dc) rs += (double)row[dc];
            s += rs;
        }
        S[b * LL + i] = s;
    }

    // wave-level f64 reduction (64 lanes); inactive lanes contribute 0
    double t = s;
    #pragma unroll
    for (int off = 32; off > 0; off >>= 1)
        t += __shfl_down(t, off, 64);
    if (threadIdx.x == 0)
        part[b * TILES_A + blockIdx.x] = t;
}

// ---------------------------------------------------------------------------
// Kernel B: 16 blocks (one per image) x 256 threads.
//  phase 0: every block independently reduces the 512 partials -> total (4 KB,
//           L2-hit; avoids atomics/memset and a third kernel)
//  phase 1: iv = log2(S * 32512 / total), staged in LDS, stored f32
//  phase 2: dv from LDS iv windows (f64), staged in LDS, stored f32
//  phase 3: band = (dv[j]<0 && dv[j+2]>0) ? 1.0f : 0.0f
// ---------------------------------------------------------------------------
__global__ __launch_bounds__(256) void kB(const double* __restrict__ S,
                                          const double* __restrict__ part,
                                          float* __restrict__ out) {
    __shared__ double red[256];
    __shared__ double ivb[LL];
    __shared__ double dvb[LD];

    const int b   = blockIdx.x;
    const int tid = threadIdx.x;

    // phase 0: total = sum over all (b,i) of S
    double p = 0.0;
    for (int t = tid; t < BATCH * TILES_A; t += 256) p += part[t];
    red[tid] = p;
    __syncthreads();
    for (int off = 128; off > 0; off >>= 1) {
        if (tid < off) red[tid] += red[tid + off];
        __syncthreads();
    }
    const double total = red[0];
    // iv = log2( (S/289) / (total/(289*32512)) ) = log2(S * 32512 / total)
    const double c = (double)(BATCH * LL) / total;

    // phase 1: iv
    for (int i = tid; i < LL; i += 256) {
        double iv = log2(S[b * LL + i] * c);
        ivb[i] = iv;
        out[b * LL + i] = (float)iv;
    }
    __syncthreads();

    // phase 2: dv
    float* out_dv = out + BATCH * LL;
    for (int j = tid; j < LD; j += 256) {
        double top = 0.0, bot = 0.0;
        #pragma unroll
        for (int t = 0; t < DS; ++t) {
            bot += ivb[j + t];
            top += ivb[j + DS + t];
        }
        double dv = (top - bot) * 0.125;
        dvb[j] = dv;
        out_dv[b * LD + j] = (float)dv;
    }
    __syncthreads();

    // phase 3: band
    float* out_band = out + BATCH * (LL + LD);
    for (int j = tid; j < LB; j += 256) {
        out_band[b * LB + j] = (dvb[j] < 0.0 && dvb[j + 2] > 0.0) ? 1.0f : 0.0f;
    }
}

extern "C" void kernel_launch(void* const* d_in, const int* in_sizes, int n_in,
                              void* d_out, int out_size, void* d_ws, size_t ws_size,
                              hipStream_t stream) {
    const float* x = (const float*)d_in[0];
    float* out = (float*)d_out;

    // ws layout: S[16*2032] f64, then part[16*32] f64  (264,192 bytes total)
    double* S    = (double*)d_ws;
    double* part = S + BATCH * LL;

    dim3 gA(TILES_A, BATCH);
    kA<<<gA, 64, 0, stream>>>(x, S, part);
    kB<<<BATCH, 256, 0, stream>>>(S, part, out);
}

// Round 2
// 16.719 us; speedup vs baseline: 1.1446x; 1.1446x over previous
//
#include <hip/hip_runtime.h>

// x: (16,1,2048,2048) f32
// iv (16,2032) f32 | dv (16,2017) f32 | band (16,2015) f32(0/1), concat flat.

#define NN    2048
#define KW    17
#define LL    2032
#define DS    8
#define LD    2017
#define LB    2015
#define BATCH 16
#define TILE  64
#define NTILES ((LL + TILE - 1) / TILE)   // 32
#define TROWS (TILE + KW - 1)             // 80
#define TCOLS (TILE + KW - 1)             // 80

// ---------------------------------------------------------------------------
// Kernel A: per (tile,b) block of 256 threads.
//  - stage 80x80 f32 tile of x (coalesced float4)
//  - V[j][c] = sum_{dr<17} tile[j+dr][c]      (vertical window sums, f32)
//  - S[i0+j] = sum_{dc<17} V[j][j+dc]         (diagonal horizontal sums, f32)
//  - f64 per-block partial sum of S for the global mean
// ---------------------------------------------------------------------------
__global__ __launch_bounds__(256) void kA(const float* __restrict__ x,
                                          float* __restrict__ S,
                                          double* __restrict__ part) {
    __shared__ float tile[TROWS * TCOLS];   // 25.6 KB
    __shared__ float V[TILE * TCOLS];       // 20.5 KB

    const int tl  = blockIdx.x;
    const int b   = blockIdx.y;
    const int i0  = tl * TILE;
    const int nout = (LL - i0 < TILE) ? (LL - i0) : TILE;   // 64 or 48
    const int tid = threadIdx.x;
    const float* xb = x + (size_t)b * NN * NN;

    // stage: rows [i0,i0+80) x cols [i0,i0+80), clamped at 2048 (unused tail)
    for (int f = tid; f < TROWS * (TCOLS / 4); f += 256) {    // 80*20
        int r  = f / (TCOLS / 4);
        int c4 = f - r * (TCOLS / 4);
        int gr = i0 + r;
        int gc = i0 + c4 * 4;
        if (gr < NN && gc + 3 < NN) {
            float4 v = *reinterpret_cast<const float4*>(xb + (size_t)gr * NN + gc);
            *reinterpret_cast<float4*>(&tile[r * TCOLS + c4 * 4]) = v;
        }
    }
    __syncthreads();

    // stage 1: vertical 17-sums (two accumulators to halve the chain)
    const int ncols = nout + KW - 1;
    for (int p = tid; p < TILE * TCOLS; p += 256) {
        int j = p / TCOLS;
        int c = p - j * TCOLS;
        if (j < nout && c < ncols) {
            float a0 = 0.f, a1 = 0.f;
            #pragma unroll
            for (int dr = 0; dr < 16; dr += 2) {
                a0 += tile[(j + dr) * TCOLS + c];
                a1 += tile[(j + dr + 1) * TCOLS + c];
            }
            a0 += tile[(j + 16) * TCOLS + c];
            V[j * TCOLS + c] = a0 + a1;
        }
    }
    __syncthreads();

    // stage 2 (wave 0): diagonal horizontal 17-sums; stride 81 words -> no
    // bank conflict worse than 2-way across 64 lanes.
    double ps = 0.0;
    if (tid < 64) {
        int j = tid;
        if (j < nout) {
            float s0 = 0.f, s1 = 0.f;
            #pragma unroll
            for (int dc = 0; dc < 16; dc += 2) {
                s0 += V[j * TCOLS + j + dc];
                s1 += V[j * TCOLS + j + dc + 1];
            }
            s0 += V[j * TCOLS + j + 16];
            float s = s0 + s1;
            S[b * LL + i0 + j] = s;
            ps = (double)s;
        }
        #pragma unroll
        for (int off = 32; off > 0; off >>= 1)
            ps += __shfl_down(ps, off, 64);
        if (tid == 0) part[b * NTILES + tl] = ps;
    }
}

// ---------------------------------------------------------------------------
// Kernel B: 16 blocks x 1024 threads (one block per image).
//  phase 0: redundant reduce of 512 f64 partials (L2-hit) -> global mean
//  phase 1: iv = log2f(S * c), staged in LDS f32
//  phase 2: dv windows from LDS
//  phase 3: band
// ---------------------------------------------------------------------------
__global__ __launch_bounds__(1024) void kB(const float* __restrict__ S,
                                           const double* __restrict__ part,
                                           float* __restrict__ out) {
    __shared__ float  ivb[LL];
    __shared__ float  dvb[LD];
    __shared__ double wred[16];

    const int b    = blockIdx.x;
    const int tid  = threadIdx.x;
    const int wid  = tid >> 6;
    const int lane = tid & 63;

    // phase 0
    double p = (tid < BATCH * NTILES) ? part[tid] : 0.0;   // 512 partials
    #pragma unroll
    for (int off = 32; off > 0; off >>= 1) p += __shfl_down(p, off, 64);
    if (lane == 0) wred[wid] = p;
    __syncthreads();
    double total = 0.0;
    #pragma unroll
    for (int w = 0; w < 16; ++w) total += wred[w];
    // iv = log2(S * (B*LL)/total); global-mean factor cancels exactly in dv.
    const float c = (float)((double)(BATCH * LL) / total);

    // phase 1: iv
    for (int i = tid; i < LL; i += 1024) {
        float iv = log2f(S[b * LL + i] * c);
        ivb[i] = iv;
        out[b * LL + i] = iv;
    }
    __syncthreads();

    // phase 2: dv
    float* out_dv = out + BATCH * LL;
    for (int j = tid; j < LD; j += 1024) {
        float t0 = 0.f, t1 = 0.f, b0 = 0.f, b1 = 0.f;
        #pragma unroll
        for (int t = 0; t < 8; t += 2) {
            b0 += ivb[j + t];
            b1 += ivb[j + t + 1];
            t0 += ivb[j + DS + t];
            t1 += ivb[j + DS + t + 1];
        }
        float dv = ((t0 + t1) - (b0 + b1)) * 0.125f;
        dvb[j] = dv;
        out_dv[b * LD + j] = dv;
    }
    __syncthreads();

    // phase 3: band
    float* out_band = out + BATCH * (LL + LD);
    for (int j = tid; j < LB; j += 1024) {
        out_band[b * LB + j] = (dvb[j] < 0.f && dvb[j + 2] > 0.f) ? 1.0f : 0.0f;
    }
}

extern "C" void kernel_launch(void* const* d_in, const int* in_sizes, int n_in,
                              void* d_out, int out_size, void* d_ws, size_t ws_size,
                              hipStream_t stream) {
    const float* x = (const float*)d_in[0];
    float* out = (float*)d_out;

    // ws: S[16*2032] f32, then part[16*32] f64 (8B-aligned: S is 130048 f32 -> pad)
    float*  S    = (float*)d_ws;
    double* part = (double*)((char*)d_ws + ((BATCH * LL * sizeof(float) + 15) & ~15));

    dim3 gA(NTILES, BATCH);
    kA<<<gA, 256, 0, stream>>>(x, S, part);
    kB<<<BATCH, 1024, 0, stream>>>(S, part, out);
}